// Round 7
// baseline (319.532 us; speedup 1.0000x reference)
//
#include <hip/hip_runtime.h>
#include <cstdint>
#include <cstddef>

#define N_NODES 100000
#define N_EDGES 3200000
#define F_IN 128
#define F_OUT 128

// ---------------- workspace layout ----------------
#define ROWPTR_BYTES ((N_NODES + 1) * 4)
#define O_XB   (((ROWPTR_BYTES) + 255) & ~255)        // 400,128
#define XB_BYTES (N_NODES * F_IN * 2)                 // 25,600,000
#define O_WT   (O_XB + XB_BYTES)                      // 26,000,128
#define WT_BYTES (F_OUT * F_IN * 2)                   // 32,768
#define NEED_A ((size_t)(O_WT + WT_BYTES))            // 26,032,896

typedef __attribute__((ext_vector_type(8))) short short8;   // 8 bf16
typedef __attribute__((ext_vector_type(4))) float f32x4;

// f32 -> bf16 round-to-nearest-even
__device__ __forceinline__ unsigned short f2bf(float f) {
    union { float f; unsigned u; } v; v.f = f;
    return (unsigned short)((v.u + 0x7FFFu + ((v.u >> 16) & 1u)) >> 16);
}
__device__ __forceinline__ float bflo(unsigned u) {
    union { unsigned u; float f; } v; v.u = u << 16; return v.f;
}
__device__ __forceinline__ float bfhi(unsigned u) {
    union { unsigned u; float f; } v; v.u = u & 0xFFFF0000u; return v.f;
}

__device__ __forceinline__ int lower_bound_i32(const int* __restrict__ a, int n, int key) {
    int lo = 0, hi = n;
    while (lo < hi) {
        int mid = (lo + hi) >> 1;
        if (a[mid] < key) lo = mid + 1; else hi = mid;
    }
    return lo;
}

// One prep kernel (3 jobs by global thread id):
//  g < 3.2M        : convert x f32 -> xb bf16 (float4 -> uint2, coalesced)
//  g <= 100000     : rowptr[g] = lower_bound(rows, g)
//  g < 16384       : Wt[c*128+k] = bf16(W[k*128+c])
__global__ __launch_bounds__(256) void prep_kernel(
    const float*    __restrict__ x4_,     // as float4 base
    const int*      __restrict__ rows,
    const float*    __restrict__ W,
    int*            __restrict__ rowptr,
    uint2*          __restrict__ xb2,
    unsigned short* __restrict__ Wt)
{
    const unsigned g = blockIdx.x * 256 + threadIdx.x;
    const float4* __restrict__ x4 = (const float4*)x4_;

    if (g < (N_NODES * F_IN / 4)) {
        const float4 a = x4[g];
        uint2 p;
        p.x = (unsigned)f2bf(a.x) | ((unsigned)f2bf(a.y) << 16);
        p.y = (unsigned)f2bf(a.z) | ((unsigned)f2bf(a.w) << 16);
        xb2[g] = p;
    }
    if (g <= N_NODES)
        rowptr[g] = lower_bound_i32(rows, N_EDGES, g);
    if (g < F_IN * F_OUT) {
        const int c = g >> 7, k = g & 127;
        Wt[g] = f2bf(W[k * F_OUT + c]);
    }
}

// Fused SpMM + MFMA GEMM:
//   phase 1 (gather): wave w gathers rows r0+w*16 .. +15 sequentially from bf16 xb
//     (lane owns 2 features, 16-deep unroll), packs bf16, writes XOR-swizzled A_lds.
//   phase 2 (MFMA): out[r,:] = relu(A_lds[r,:] @ Wt^T + b); B-frags direct from
//     global Wt (32KB, L1-resident). LDS = 16KB only -> whole grid co-resident.
// A_lds swizzle: element k of row r at byte r*256 + ((2k) ^ ((r&7)<<4)).
__global__ __launch_bounds__(256) void fused_spmm_gemm(
    const unsigned*       __restrict__ xb,
    const int*            __restrict__ cols,
    const float*          __restrict__ vals,
    const int*            __restrict__ rowptr,
    const unsigned short* __restrict__ Wt,
    const float*          __restrict__ bias,
    float*                __restrict__ out)
{
    __shared__ char A_lds[64 * 256];   // 16 KB, bf16 swizzled

    const int t    = threadIdx.x;
    const int lane = t & 63;
    const int w    = t >> 6;
    const int r0   = blockIdx.x * 64;

    // ---------- phase 1: gather 16 rows per wave ----------
    for (int i = 0; i < 16; ++i) {
        const int lrow = w * 16 + i;
        const int row  = r0 + lrow;
        float ax = 0.f, ay = 0.f;
        if (row < N_NODES) {
            const int e0 = rowptr[row], e1 = rowptr[row + 1];
            int e = e0;
            for (; e + 16 <= e1; e += 16) {
                int c[16]; float v[16]; unsigned u[16];
                #pragma unroll
                for (int j = 0; j < 16; ++j) { c[j] = cols[e + j]; v[j] = vals[e + j]; }
                #pragma unroll
                for (int j = 0; j < 16; ++j) u[j] = xb[(unsigned)c[j] * 64u + lane];
                #pragma unroll
                for (int j = 0; j < 16; ++j) {
                    ax = fmaf(v[j], bflo(u[j]), ax);
                    ay = fmaf(v[j], bfhi(u[j]), ay);
                }
            }
            for (; e + 4 <= e1; e += 4) {
                int c[4]; float v[4]; unsigned u[4];
                #pragma unroll
                for (int j = 0; j < 4; ++j) { c[j] = cols[e + j]; v[j] = vals[e + j]; }
                #pragma unroll
                for (int j = 0; j < 4; ++j) u[j] = xb[(unsigned)c[j] * 64u + lane];
                #pragma unroll
                for (int j = 0; j < 4; ++j) {
                    ax = fmaf(v[j], bflo(u[j]), ax);
                    ay = fmaf(v[j], bfhi(u[j]), ay);
                }
            }
            for (; e < e1; ++e) {
                const float v = vals[e];
                const unsigned u = xb[(unsigned)cols[e] * 64u + lane];
                ax = fmaf(v, bflo(u), ax);
                ay = fmaf(v, bfhi(u), ay);
            }
        }
        // lane owns features 2*lane, 2*lane+1 -> 4B at elem-byte 4*lane, swizzled
        const unsigned p = (unsigned)f2bf(ax) | ((unsigned)f2bf(ay) << 16);
        *reinterpret_cast<unsigned*>(
            A_lds + lrow * 256 + ((lane * 4) ^ ((lrow & 7) << 4))) = p;
    }
    __syncthreads();

    // ---------- phase 2: MFMA (wave w -> rows w*16..w*16+15, all 128 cols) ----------
    const int lr = lane & 15;          // A-row / B-col in tile
    const int lg = lane >> 4;          // k-chunk group
    const int swA = (lr & 7) << 4;

    const short* __restrict__ Wbase =
        reinterpret_cast<const short*>(Wt) + lr * F_IN + lg * 8;
    const char* Abase = A_lds + (w * 16 + lr) * 256;

    f32x4 acc[8];
    #pragma unroll
    for (int n = 0; n < 8; ++n) acc[n] = (f32x4){0.f, 0.f, 0.f, 0.f};

    #pragma unroll
    for (int ks = 0; ks < 4; ++ks) {
        const short8 a = *reinterpret_cast<const short8*>(
            Abase + ((ks * 64 + lg * 16) ^ swA));
        #pragma unroll
        for (int n = 0; n < 8; ++n) {
            const short8 b = *reinterpret_cast<const short8*>(
                Wbase + n * 16 * F_IN + ks * 32);
            acc[n] = __builtin_amdgcn_mfma_f32_16x16x32_bf16(a, b, acc[n], 0, 0, 0);
        }
    }

    // C/D layout (verified): col = n*16 + (lane&15), row = w*16 + (lane>>4)*4 + reg
    const int row_base = r0 + w * 16 + lg * 4;
    #pragma unroll
    for (int n = 0; n < 8; ++n) {
        const int col = n * 16 + lr;
        const float bb = bias[col];
        #pragma unroll
        for (int reg = 0; reg < 4; ++reg) {
            const int r = row_base + reg;
            if (r < N_NODES)
                out[(size_t)r * F_OUT + col] = fmaxf(acc[n][reg] + bb, 0.f);
        }
    }
}

// ---------------- fallback (no workspace): f32 spmm -> in-place LDS mfma gemm ----------------
__global__ __launch_bounds__(256) void spmm_ax_fallback(
    const float* __restrict__ x,
    const int*   __restrict__ rows,
    const int*   __restrict__ cols,
    const float* __restrict__ vals,
    float*       __restrict__ out)
{
    const int row  = blockIdx.x * 4 + (threadIdx.x >> 6);
    const int lane = threadIdx.x & 63;
    if (row >= N_NODES) return;
    const int e0 = lower_bound_i32(rows, N_EDGES, row);
    const int e1 = lower_bound_i32(rows, N_EDGES, row + 1);
    const float2* __restrict__ x2 = reinterpret_cast<const float2*>(x);
    float ax = 0.f, ay = 0.f;
    int e = e0;
    for (; e + 8 <= e1; e += 8) {
        int c[8]; float v[8]; float2 a[8];
        #pragma unroll
        for (int j = 0; j < 8; ++j) { c[j] = cols[e + j]; v[j] = vals[e + j]; }
        #pragma unroll
        for (int j = 0; j < 8; ++j) a[j] = x2[(unsigned)c[j] * 64u + lane];
        #pragma unroll
        for (int j = 0; j < 8; ++j) {
            ax = fmaf(v[j], a[j].x, ax); ay = fmaf(v[j], a[j].y, ay);
        }
    }
    for (; e < e1; ++e) {
        const float v = vals[e];
        const float2 a = x2[(unsigned)cols[e] * 64u + lane];
        ax = fmaf(v, a.x, ax); ay = fmaf(v, a.y, ay);
    }
    float2 o; o.x = ax; o.y = ay;
    reinterpret_cast<float2*>(out)[(size_t)row * 64 + lane] = o;
}

__global__ __launch_bounds__(256) void gemm_inplace_fallback(
    float*       __restrict__ out,
    const float* __restrict__ W,
    const float* __restrict__ bias)
{
    __shared__ short A_lds[64][136];
    __shared__ short Wt_lds[F_OUT][136];
    const int t  = threadIdx.x;
    const int r0 = blockIdx.x * 64;
    const int rows_here = (N_NODES - r0 < 64) ? (N_NODES - r0) : 64;
    {
        const float4* __restrict__ A4 =
            reinterpret_cast<const float4*>(out + (size_t)r0 * F_IN);
        const int nA = rows_here * 32;
        for (int i = t; i < nA; i += 256) {
            const int r = i >> 5, q = i & 31;
            const float4 va = A4[i];
            uint2 p;
            p.x = (unsigned)f2bf(va.x) | ((unsigned)f2bf(va.y) << 16);
            p.y = (unsigned)f2bf(va.z) | ((unsigned)f2bf(va.w) << 16);
            *reinterpret_cast<uint2*>(&A_lds[r][q * 4]) = p;
        }
    }
    if (t < F_OUT)
        for (int k = 0; k < F_IN; ++k)
            Wt_lds[t][k] = (short)f2bf(W[k * F_OUT + t]);
    __syncthreads();

    const int lane = t & 63, w = t >> 6, lr = lane & 15, lg = lane >> 4;
    f32x4 acc[8];
    #pragma unroll
    for (int n = 0; n < 8; ++n) acc[n] = (f32x4){0.f, 0.f, 0.f, 0.f};
    #pragma unroll
    for (int ks = 0; ks < 4; ++ks) {
        const short8 a = *reinterpret_cast<const short8*>(
            &A_lds[w * 16 + lr][ks * 32 + lg * 8]);
        #pragma unroll
        for (int n = 0; n < 8; ++n) {
            const short8 b = *reinterpret_cast<const short8*>(
                &Wt_lds[n * 16 + lr][ks * 32 + lg * 8]);
            acc[n] = __builtin_amdgcn_mfma_f32_16x16x32_bf16(a, b, acc[n], 0, 0, 0);
        }
    }
    const int row_base = r0 + w * 16 + lg * 4;
    #pragma unroll
    for (int n = 0; n < 8; ++n) {
        const int col = n * 16 + lr;
        const float bb = bias[col];
        #pragma unroll
        for (int reg = 0; reg < 4; ++reg) {
            const int r = row_base + reg;
            if (r < N_NODES)
                out[(size_t)r * F_OUT + col] = fmaxf(acc[n][reg] + bb, 0.f);
        }
    }
}

extern "C" void kernel_launch(void* const* d_in, const int* in_sizes, int n_in,
                              void* d_out, int out_size, void* d_ws, size_t ws_size,
                              hipStream_t stream) {
    const float* x    = (const float*)d_in[0];
    const int*   rows = (const int*)  d_in[1];
    const int*   cols = (const int*)  d_in[2];
    const float* vals = (const float*)d_in[3];
    const float* W    = (const float*)d_in[4];
    const float* b    = (const float*)d_in[5];
    float* out = (float*)d_out;
    char*  ws  = (char*)d_ws;

    if (ws_size >= NEED_A) {
        int*            rowptr = (int*)ws;
        unsigned short* xb     = (unsigned short*)(ws + O_XB);
        unsigned short* Wt     = (unsigned short*)(ws + O_WT);
        // grid covers max(3.2M convert, 100001 rowptr, 16384 wt)
        prep_kernel<<<(N_NODES * F_IN / 4 + 255) / 256, 256, 0, stream>>>(
            x, rows, W, rowptr, (uint2*)xb, Wt);
        fused_spmm_gemm<<<(N_NODES + 63) / 64, 256, 0, stream>>>(
            (const unsigned*)xb, cols, vals, rowptr, Wt, b, out);
    } else {
        spmm_ax_fallback<<<(N_NODES + 3) / 4, 256, 0, stream>>>(
            x, rows, cols, vals, out);
        gemm_inplace_fallback<<<(N_NODES + 63) / 64, 256, 0, stream>>>(out, W, b);
    }
}

// Round 9
// 291.465 us; speedup vs baseline: 1.0963x; 1.0963x over previous
//
#include <hip/hip_runtime.h>
#include <cstdint>
#include <cstddef>

#define N_NODES 100000
#define N_EDGES 3200000
#define F_IN 128
#define F_OUT 128

// ---------------- workspace layout ----------------
#define ROWPTR_BYTES ((N_NODES + 1) * 4)
#define O_XB   (((ROWPTR_BYTES) + 255) & ~255)        // 400,128
#define XB_BYTES (N_NODES * F_IN * 2)                 // 25,600,000
#define O_WT   (O_XB + XB_BYTES)                      // 26,000,128
#define WT_BYTES (F_OUT * F_IN * 2)                   // 32,768
#define NEED_A ((size_t)(O_WT + WT_BYTES))            // 26,032,896

typedef __attribute__((ext_vector_type(8))) short short8;   // 8 bf16
typedef __attribute__((ext_vector_type(4))) float f32x4;

// f32 -> bf16 round-to-nearest-even
__device__ __forceinline__ unsigned short f2bf(float f) {
    union { float f; unsigned u; } v; v.f = f;
    return (unsigned short)((v.u + 0x7FFFu + ((v.u >> 16) & 1u)) >> 16);
}
__device__ __forceinline__ float bflo(unsigned u) {
    union { unsigned u; float f; } v; v.u = u << 16; return v.f;
}
__device__ __forceinline__ float bfhi(unsigned u) {
    union { unsigned u; float f; } v; v.u = u & 0xFFFF0000u; return v.f;
}

__device__ __forceinline__ int lower_bound_i32(const int* __restrict__ a, int n, int key) {
    int lo = 0, hi = n;
    while (lo < hi) {
        int mid = (lo + hi) >> 1;
        if (a[mid] < key) lo = mid + 1; else hi = mid;
    }
    return lo;
}

// convert x f32 -> xb bf16 (float4 -> uint2, coalesced). Separate kernel for
// rocprof attribution (r7's merged prep looked anomalously slow in residuals).
__global__ __launch_bounds__(256) void convert_x_kernel(
    const float4* __restrict__ x4, uint2* __restrict__ xb2)
{
    const unsigned g = blockIdx.x * 256 + threadIdx.x;
    if (g < (N_NODES * F_IN / 4)) {
        const float4 a = x4[g];
        uint2 p;
        p.x = (unsigned)f2bf(a.x) | ((unsigned)f2bf(a.y) << 16);
        p.y = (unsigned)f2bf(a.z) | ((unsigned)f2bf(a.w) << 16);
        xb2[g] = p;
    }
}

// rowptr (g <= 100000) + Wt transpose (g < 16384); 391 blocks
__global__ __launch_bounds__(256) void aux_kernel(
    const int*      __restrict__ rows,
    const float*    __restrict__ W,
    int*            __restrict__ rowptr,
    unsigned short* __restrict__ Wt)
{
    const unsigned g = blockIdx.x * 256 + threadIdx.x;
    if (g <= N_NODES)
        rowptr[g] = lower_bound_i32(rows, N_EDGES, g);
    if (g < F_IN * F_OUT) {
        const int c = g >> 7, k = g & 127;
        Wt[g] = f2bf(W[k * F_OUT + c]);
    }
}

// Fused SpMM + MFMA GEMM, 1024 threads / 16 waves per block, 64 rows per block.
//  phase 1: wave w gathers rows w*4 .. w*4+3 (lane owns 2 features, 16-deep MLP),
//           writes bf16 XOR-swizzled into the 16 KB A_lds tile.
//  phase 2: wave w -> rows (w&3)*16..+15, cols (w>>2)*32..+31; B-frags direct
//           from global Wt (32 KB, L1-hot).
// Occupancy: 2 blocks/CU (wave cap) = 32 waves/CU = 100%; LDS 2x16 KB.
// A_lds swizzle: element-pair byte addr = row*256 + ((4*lane) ^ ((row&7)<<4)).
__global__ __launch_bounds__(1024, 8) void fused_spmm_gemm(
    const unsigned*       __restrict__ xb,
    const int*            __restrict__ cols,
    const float*          __restrict__ vals,
    const int*            __restrict__ rowptr,
    const unsigned short* __restrict__ Wt,
    const float*          __restrict__ bias,
    float*                __restrict__ out)
{
    __shared__ char A_lds[64 * 256];   // 16 KB bf16, swizzled

    const int t    = threadIdx.x;
    const int lane = t & 63;
    const int w    = t >> 6;           // 0..15
    const int r0   = blockIdx.x * 64;

    // ---------- phase 1: each wave gathers 4 rows ----------
    for (int i = 0; i < 4; ++i) {
        const int lrow = w * 4 + i;
        const int row  = r0 + lrow;
        float ax = 0.f, ay = 0.f;
        if (row < N_NODES) {
            const int e0 = rowptr[row], e1 = rowptr[row + 1];
            int e = e0;
            for (; e + 16 <= e1; e += 16) {
                int c[16]; float v[16]; unsigned u[16];
                #pragma unroll
                for (int j = 0; j < 16; ++j) { c[j] = cols[e + j]; v[j] = vals[e + j]; }
                #pragma unroll
                for (int j = 0; j < 16; ++j) u[j] = xb[(unsigned)c[j] * 64u + lane];
                #pragma unroll
                for (int j = 0; j < 16; ++j) {
                    ax = fmaf(v[j], bflo(u[j]), ax);
                    ay = fmaf(v[j], bfhi(u[j]), ay);
                }
            }
            for (; e + 4 <= e1; e += 4) {
                int c[4]; float v[4]; unsigned u[4];
                #pragma unroll
                for (int j = 0; j < 4; ++j) { c[j] = cols[e + j]; v[j] = vals[e + j]; }
                #pragma unroll
                for (int j = 0; j < 4; ++j) u[j] = xb[(unsigned)c[j] * 64u + lane];
                #pragma unroll
                for (int j = 0; j < 4; ++j) {
                    ax = fmaf(v[j], bflo(u[j]), ax);
                    ay = fmaf(v[j], bfhi(u[j]), ay);
                }
            }
            for (; e < e1; ++e) {
                const float v = vals[e];
                const unsigned u = xb[(unsigned)cols[e] * 64u + lane];
                ax = fmaf(v, bflo(u), ax);
                ay = fmaf(v, bfhi(u), ay);
            }
        }
        const unsigned p = (unsigned)f2bf(ax) | ((unsigned)f2bf(ay) << 16);
        *reinterpret_cast<unsigned*>(
            A_lds + lrow * 256 + ((lane * 4) ^ ((lrow & 7) << 4))) = p;
    }
    __syncthreads();

    // ---------- phase 2: wave w -> row-tile (w&3), col-group (w>>2) ----------
    const int rt = w & 3;              // row tile: rows rt*16..+15
    const int cg = w >> 2;             // col group: cols cg*32..+31
    const int lr = lane & 15;
    const int lg = lane >> 4;
    const int swA = (lr & 7) << 4;

    const char* Abase = A_lds + (rt * 16 + lr) * 256;

    f32x4 acc[2];
    acc[0] = (f32x4){0.f, 0.f, 0.f, 0.f};
    acc[1] = (f32x4){0.f, 0.f, 0.f, 0.f};

    #pragma unroll
    for (int ks = 0; ks < 4; ++ks) {
        const short8 a = *reinterpret_cast<const short8*>(
            Abase + ((ks * 64 + lg * 16) ^ swA));
        #pragma unroll
        for (int nn = 0; nn < 2; ++nn) {
            const short8 b = *reinterpret_cast<const short8*>(
                reinterpret_cast<const short*>(Wt) +
                (cg * 32 + nn * 16 + lr) * F_IN + lg * 8 + ks * 32);
            acc[nn] = __builtin_amdgcn_mfma_f32_16x16x32_bf16(a, b, acc[nn], 0, 0, 0);
        }
    }

    // C/D (verified): col = cg*32 + nn*16 + (lane&15), row = rt*16 + (lane>>4)*4 + reg
    const int row_base = r0 + rt * 16 + lg * 4;
    #pragma unroll
    for (int nn = 0; nn < 2; ++nn) {
        const int col = cg * 32 + nn * 16 + lr;
        const float bb = bias[col];
        #pragma unroll
        for (int reg = 0; reg < 4; ++reg) {
            const int r = row_base + reg;
            if (r < N_NODES)
                out[(size_t)r * F_OUT + col] = fmaxf(acc[nn][reg] + bb, 0.f);
        }
    }
}

// ---------------- fallback (no workspace) ----------------
__global__ __launch_bounds__(256) void spmm_ax_fallback(
    const float* __restrict__ x,
    const int*   __restrict__ rows,
    const int*   __restrict__ cols,
    const float* __restrict__ vals,
    float*       __restrict__ out)
{
    const int row  = blockIdx.x * 4 + (threadIdx.x >> 6);
    const int lane = threadIdx.x & 63;
    if (row >= N_NODES) return;
    const int e0 = lower_bound_i32(rows, N_EDGES, row);
    const int e1 = lower_bound_i32(rows, N_EDGES, row + 1);
    const float2* __restrict__ x2 = reinterpret_cast<const float2*>(x);
    float ax = 0.f, ay = 0.f;
    int e = e0;
    for (; e + 8 <= e1; e += 8) {
        int c[8]; float v[8]; float2 a[8];
        #pragma unroll
        for (int j = 0; j < 8; ++j) { c[j] = cols[e + j]; v[j] = vals[e + j]; }
        #pragma unroll
        for (int j = 0; j < 8; ++j) a[j] = x2[(unsigned)c[j] * 64u + lane];
        #pragma unroll
        for (int j = 0; j < 8; ++j) {
            ax = fmaf(v[j], a[j].x, ax); ay = fmaf(v[j], a[j].y, ay);
        }
    }
    for (; e < e1; ++e) {
        const float v = vals[e];
        const float2 a = x2[(unsigned)cols[e] * 64u + lane];
        ax = fmaf(v, a.x, ax); ay = fmaf(v, a.y, ay);
    }
    float2 o; o.x = ax; o.y = ay;
    reinterpret_cast<float2*>(out)[(size_t)row * 64 + lane] = o;
}

__global__ __launch_bounds__(256) void gemm_inplace_fallback(
    float*       __restrict__ out,
    const float* __restrict__ W,
    const float* __restrict__ bias)
{
    __shared__ short A_lds[64][136];
    __shared__ short Wt_lds[F_OUT][136];
    const int t  = threadIdx.x;
    const int r0 = blockIdx.x * 64;
    const int rows_here = (N_NODES - r0 < 64) ? (N_NODES - r0) : 64;
    {
        const float4* __restrict__ A4 =
            reinterpret_cast<const float4*>(out + (size_t)r0 * F_IN);
        const int nA = rows_here * 32;
        for (int i = t; i < nA; i += 256) {
            const int r = i >> 5, q = i & 31;
            const float4 va = A4[i];
            uint2 p;
            p.x = (unsigned)f2bf(va.x) | ((unsigned)f2bf(va.y) << 16);
            p.y = (unsigned)f2bf(va.z) | ((unsigned)f2bf(va.w) << 16);
            *reinterpret_cast<uint2*>(&A_lds[r][q * 4]) = p;
        }
    }
    if (t < F_OUT)
        for (int k = 0; k < F_IN; ++k)
            Wt_lds[t][k] = (short)f2bf(W[k * F_OUT + t]);
    __syncthreads();

    const int lane = t & 63, w = t >> 6, lr = lane & 15, lg = lane >> 4;
    f32x4 acc[8];
    #pragma unroll
    for (int n = 0; n < 8; ++n) acc[n] = (f32x4){0.f, 0.f, 0.f, 0.f};
    #pragma unroll
    for (int ks = 0; ks < 4; ++ks) {
        const short8 a = *reinterpret_cast<const short8*>(
            &A_lds[w * 16 + lr][ks * 32 + lg * 8]);
        #pragma unroll
        for (int n = 0; n < 8; ++n) {
            const short8 b = *reinterpret_cast<const short8*>(
                &Wt_lds[n * 16 + lr][ks * 32 + lg * 8]);
            acc[n] = __builtin_amdgcn_mfma_f32_16x16x32_bf16(a, b, acc[n], 0, 0, 0);
        }
    }
    const int row_base = r0 + w * 16 + lg * 4;
    #pragma unroll
    for (int n = 0; n < 8; ++n) {
        const int col = n * 16 + lr;
        const float bb = bias[col];
        #pragma unroll
        for (int reg = 0; reg < 4; ++reg) {
            const int r = row_base + reg;
            if (r < N_NODES)
                out[(size_t)r * F_OUT + col] = fmaxf(acc[n][reg] + bb, 0.f);
        }
    }
}

extern "C" void kernel_launch(void* const* d_in, const int* in_sizes, int n_in,
                              void* d_out, int out_size, void* d_ws, size_t ws_size,
                              hipStream_t stream) {
    const float* x    = (const float*)d_in[0];
    const int*   rows = (const int*)  d_in[1];
    const int*   cols = (const int*)  d_in[2];
    const float* vals = (const float*)d_in[3];
    const float* W    = (const float*)d_in[4];
    const float* b    = (const float*)d_in[5];
    float* out = (float*)d_out;
    char*  ws  = (char*)d_ws;

    if (ws_size >= NEED_A) {
        int*            rowptr = (int*)ws;
        unsigned short* xb     = (unsigned short*)(ws + O_XB);
        unsigned short* Wt     = (unsigned short*)(ws + O_WT);
        convert_x_kernel<<<(N_NODES * F_IN / 4 + 255) / 256, 256, 0, stream>>>(
            (const float4*)x, (uint2*)xb);
        aux_kernel<<<(N_NODES + 256) / 256, 256, 0, stream>>>(rows, W, rowptr, Wt);
        fused_spmm_gemm<<<(N_NODES + 63) / 64, 1024, 0, stream>>>(
            (const unsigned*)xb, cols, vals, rowptr, Wt, b, out);
    } else {
        spmm_ax_fallback<<<(N_NODES + 3) / 4, 256, 0, stream>>>(
            x, rows, cols, vals, out);
        gemm_inplace_fallback<<<(N_NODES + 63) / 64, 256, 0, stream>>>(out, W, b);
    }
}